// Round 17
// baseline (256.165 us; speedup 1.0000x reference)
//
#include <hip/hip_runtime.h>
#include <hip/hip_bf16.h>
#include <stdint.h>

#define IMG_H 96
#define IMG_W 96
#define IMG_C 3
#define HO    90                 // 96-7+1
#define NPAT  8100               // 90*90
#define NPAD  8192
#define DDIM  147                // 3*7*7
#define KPAD  160                // padded K (5 chunks of 32)
#define NCHK  5
#define BATCH 4
#define PNL   64                 // panel rows per block
#define SRT   128                // stream rows per tile
#define NT    (NPAD / SRT)       // 64 stream tiles
#define ALPHA 0.05f

typedef __attribute__((ext_vector_type(8))) short short8;
typedef __attribute__((ext_vector_type(4))) float f32x4;

__device__ __forceinline__ void async16(const void* g, void* l) {
    __builtin_amdgcn_global_load_lds(
        (const __attribute__((address_space(1))) unsigned int*)g,
        (__attribute__((address_space(3))) unsigned int*)l,
        16, 0, 0);
}

// ---------- patch extraction + squared norms (+ out zero) ----------
__global__ __launch_bounds__(256) void extract_patches(
    const float* __restrict__ img,          // [B][3][96][96]
    __hip_bfloat16* __restrict__ pat,       // [B][NPAD][KPAD]
    float* __restrict__ nrm,                // [B][NPAD]
    float* __restrict__ outzero)            // may be null
{
    int wid  = threadIdx.x >> 6;
    int lane = threadIdx.x & 63;
    int pidx = blockIdx.x * 4 + wid;        // 0..8191
    int b    = blockIdx.y;
    if (pidx >= NPAD) return;
    if (outzero && blockIdx.x == 0 && blockIdx.y == 0 && threadIdx.x == 0)
        outzero[0] = 0.f;
    const float* im = img + (size_t)b * (IMG_C * IMG_H * IMG_W);
    __hip_bfloat16* pp = pat + ((size_t)b * NPAD + pidx) * KPAD;
    int r = pidx / HO, c = pidx - r * HO;
    bool valid = pidx < NPAT;
    float ss = 0.f;
    for (int d = lane; d < KPAD; d += 64) {
        float v = 0.f;
        if (valid && d < DDIM) {
            int ch  = d / 49;
            int rem = d - ch * 49;
            int pr  = rem / 7, pc = rem - pr * 7;
            v = im[ch * (IMG_H * IMG_W) + (r + pr) * IMG_W + (c + pc)];
        }
        pp[d] = __float2bfloat16(v);
        ss += v * v;
    }
    for (int s = 32; s; s >>= 1) ss += __shfl_down(ss, s);
    if (lane == 0) nrm[(size_t)b * NPAD + pidx] = ss;
}

// ---------- prep: (y2, rms) float2; rms = invD/(row_min+a), inf on pads ----------
__global__ __launch_bounds__(256) void prep_rms(
    const float* __restrict__ row_min, const float* __restrict__ y2,
    float2* __restrict__ yr)
{
    int i = blockIdx.x * 256 + threadIdx.x;
    if (i < BATCH * NPAD) {
        int j = i & (NPAD - 1);
        float rm = row_min[i];
        float rr = (j < NPAT) ? (1.0f / (float)DDIM) / (rm + ALPHA)
                              : __builtin_inff();
        yr[i] = make_float2(y2[i], rr);
    }
}

// -------- panel-persistent, depth-3 ROTATING REGISTER stream queue ----------
// 512 blocks x 512 threads. Panel (64 rows) in p_reg[5][4] (one-shot 20 KB
// LDS stage, then LDS dead). Stream fragments + scalars load DIRECTLY into a
// 3-deep rotating register queue (fA/fB/fC, statically indexed): the compiler
// tracks register dataflow and emits COUNTED vmcnt before each use (the R15
// discipline without LDS). No barriers / LDS / lgkm in the loop. Eliminates
// per-tile 6 LDS writes + 5 ds_read + lgkm drain vs R16.
// PASS 1: row-min in regs -> plain store per panel row (no atomics).
// PASS 2: col-min in regs -> one atomicAdd partial per block.
template <int PASS>
__global__ __launch_bounds__(512, 2) void panel_pass(
    const __hip_bfloat16* __restrict__ Xp,   // [B][NPAD][KPAD]
    const __hip_bfloat16* __restrict__ Yp,   // [B][NPAD][KPAD]
    const float* __restrict__ x2,
    const float* __restrict__ y2,
    const float2* __restrict__ yr,           // PASS2: (y2, rms) pairs
    float* __restrict__ row_min,
    float* __restrict__ out)                 // PASS2 only
{
    __shared__ __align__(16) __hip_bfloat16 S[NCHK * PNL * 32];  // 20480 B

    int blk = blockIdx.x;
    int bz  = blk & 3;               // image: fixed per XCD under %8 rr
    int tP  = blk >> 2;              // panel index 0..127
    int tid = threadIdx.x;
    int wid = tid >> 6, lane = tid & 63;
    int fr  = lane & 15;
    int koq = lane >> 4;             // k-quad 0..3

    const __hip_bfloat16* Pbase =
        (PASS == 1 ? Yp : Xp) + ((size_t)bz * NPAD + tP * PNL) * KPAD;
    const __hip_bfloat16* Sbase =
        (PASS == 1 ? Xp : Yp) + (size_t)bz * NPAD * KPAD;
    const float*  sx2 = x2 + (size_t)bz * NPAD;
    const float2* syr = yr + (size_t)bz * NPAD;

    // ---- one-shot panel stage (waves 0-3) + p_reg load; LDS dead after ----
    if (wid < 4) {
        int row  = wid * 16 + (lane >> 2);
        int slog = (lane & 3) ^ ((row >> 1) & 3);          // inverse swz on src
        const __hip_bfloat16* src = Pbase + (size_t)row * KPAD + slog * 8;
        __hip_bfloat16* dst = &S[wid * 512];
        for (int c = 0; c < NCHK; ++c)
            async16(src + c * 32, dst + c * 4096);
    }
    __syncthreads();

    int sread = (koq ^ ((lane >> 1) & 3)) * 8;             // swizzled 16B slot
    short8 p_reg[NCHK][4];
#pragma unroll
    for (int c = 0; c < NCHK; ++c)
#pragma unroll
        for (int m = 0; m < 4; ++m)
            p_reg[c][m] =
                *(const short8*)&S[c * 4096 + (m * 16 + fr) * 32 + sread];

    float xv[4];   // PASS2: panel cols' x2 (direct global, once)
    if (PASS == 2)
#pragma unroll
        for (int nb = 0; nb < 4; ++nb)
            xv[nb] = x2[(size_t)bz * NPAD + tP * PNL + nb * 16 + fr];

    __syncthreads();   // all waves past p_reg reads; S reusable at epilogue

    float runmin[PASS == 1 ? 16 : 4];
#pragma unroll
    for (int i = 0; i < (PASS == 1 ? 16 : 4); ++i)
        runmin[i] = __builtin_inff();

    int srow = wid * 16 + fr;        // wave's stream slice row within tile
    const __hip_bfloat16* sp = Sbase + (size_t)srow * KPAD + koq * 8;

    // ---- depth-3 rotating register queue ----
    short8 fA[NCHK], fB[NCHK], fC[NCHK];
    float  gA, gB, gC;               // PASS1 scalars
    float2 qA[4], qB[4], qC[4];      // PASS2 scalars

    auto loadf = [&](short8 (&f)[NCHK], float& g, float2 (&q)[4], int t) {
        const __hip_bfloat16* p = sp + (size_t)t * SRT * KPAD;
#pragma unroll
        for (int c = 0; c < NCHK; ++c)
            f[c] = *(const short8*)(p + c * 32);
        if (PASS == 1) {
            int ic = t * SRT + srow;
            g = sx2[ic < NPAT ? ic : 0];   // pad fix applied at use (t==63)
        } else {
#pragma unroll
            for (int reg = 0; reg < 4; ++reg)
                q[reg] = syr[t * SRT + wid * 16 + koq * 4 + reg];
        }
    };

    auto body = [&](short8 (&f)[NCHK], float g, float2 (&q)[4], int t) {
        f32x4 acc[4] = {};
#pragma unroll
        for (int c = 0; c < NCHK; ++c) {
            if (PASS == 1) {
#pragma unroll
                for (int m = 0; m < 4; ++m)
                    acc[m] = __builtin_amdgcn_mfma_f32_16x16x32_bf16(
                        p_reg[c][m], f[c], acc[m], 0, 0, 0);
            } else {
#pragma unroll
                for (int nb = 0; nb < 4; ++nb)
                    acc[nb] = __builtin_amdgcn_mfma_f32_16x16x32_bf16(
                        f[c], p_reg[c][nb], acc[nb], 0, 0, 0);
            }
        }
        if (PASS == 1) {
            float xg = (t * SRT + srow < NPAT) ? g : __builtin_inff();
#pragma unroll
            for (int m = 0; m < 4; ++m)
#pragma unroll
                for (int reg = 0; reg < 4; ++reg)
                    runmin[m * 4 + reg] = fminf(runmin[m * 4 + reg],
                        fmaf(-2.0f, acc[m][reg], xg));
        } else {
#pragma unroll
            for (int reg = 0; reg < 4; ++reg) {
                float yv = q[reg].x, rr = q[reg].y;   // rr=inf on pad rows
#pragma unroll
                for (int nb = 0; nb < 4; ++nb)
                    runmin[nb] = fminf(runmin[nb],
                        fmaf(-2.0f, acc[nb][reg], yv + xv[nb]) * rr);
            }
        }
    };

    // prologue: 3 tiles in flight (15-18 VMEM/wave)
    loadf(fA, gA, qA, 0);
    loadf(fB, gB, qB, 1);
    loadf(fC, gC, qC, 2);

    int t = 0;
#pragma unroll 1
    for (int tt = 0; tt < 20; ++tt) {   // bodies t=0..59, loads tiles 3..62
        body(fA, gA, qA, t);     loadf(fA, gA, qA, t + 3);
        body(fB, gB, qB, t + 1); loadf(fB, gB, qB, t + 4);
        body(fC, gC, qC, t + 2); loadf(fC, gC, qC, t + 5);
        t += 3;
    }
    // tail: t = 60..63 (fA holds 63 after loop's last loads: 60+3)
    body(fA, gA, qA, 60); loadf(fA, gA, qA, 63);
    body(fB, gB, qB, 61);
    body(fC, gC, qC, 62);
    body(fA, gA, qA, 63);

    // ---- epilogue: red[] aliases S (dead since pre-loop barrier) ----
    float* red = (float*)&S[0];      // [8][PNL]

    if (PASS == 1) {
#pragma unroll
        for (int m = 0; m < 4; ++m)
#pragma unroll
            for (int reg = 0; reg < 4; ++reg) {
                float v = runmin[m * 4 + reg];
                for (int s = 1; s < 16; s <<= 1)
                    v = fminf(v, __shfl_xor(v, s));
                if (fr == 0)
                    red[wid * PNL + m * 16 + koq * 4 + reg] = v;
            }
        __syncthreads();
        if (tid < PNL) {
            float mv = red[tid];
#pragma unroll
            for (int w = 1; w < 8; ++w) mv = fminf(mv, red[w * PNL + tid]);
            float y2g = y2[(size_t)bz * NPAD + tP * PNL + tid];
            row_min[(size_t)bz * NPAD + tP * PNL + tid] =
                fmaxf(y2g + mv, 0.f) * (1.0f / (float)DDIM);
        }
    } else {
#pragma unroll
        for (int nb = 0; nb < 4; ++nb) {
            float v = runmin[nb];
            v = fminf(v, __shfl_xor(v, 16));
            v = fminf(v, __shfl_xor(v, 32));
            if (lane < 16) red[wid * PNL + nb * 16 + lane] = v;
        }
        __syncthreads();
        if (tid < PNL) {
            int gc = tP * PNL + tid;
            float cv = red[tid];
#pragma unroll
            for (int w = 1; w < 8; ++w) cv = fminf(cv, red[w * PNL + tid]);
            cv = fmaxf(cv, 0.f);                   // deferred clamp (monotone)
            float s = (gc < NPAT) ? cv : 0.f;      // mask pad cols
            for (int o = 32; o; o >>= 1) s += __shfl_down(s, o);
            if (tid == 0)
                atomicAdd(out, s * (1.0f / (float)(BATCH * NPAT)));
        }
    }
}

extern "C" void kernel_launch(void* const* d_in, const int* in_sizes, int n_in,
                              void* d_out, int out_size, void* d_ws, size_t ws_size,
                              hipStream_t stream) {
    const float* x = (const float*)d_in[0];
    const float* y = (const float*)d_in[1];
    float* out = (float*)d_out;

    char* ws = (char*)d_ws;
    size_t patSz = (size_t)BATCH * NPAD * KPAD * sizeof(__hip_bfloat16); // 10.5 MB
    __hip_bfloat16* Xp = (__hip_bfloat16*)ws;
    __hip_bfloat16* Yp = (__hip_bfloat16*)(ws + patSz);
    float* x2 = (float*)(ws + 2 * patSz);
    float* y2 = x2 + BATCH * NPAD;
    float* row_min = y2 + BATCH * NPAD;
    float2* yr = (float2*)(row_min + BATCH * NPAD);

    dim3 eg(NPAD / 4, BATCH);
    extract_patches<<<eg, 256, 0, stream>>>(x, Xp, x2, out);   // zeroes out
    extract_patches<<<eg, 256, 0, stream>>>(y, Yp, y2, nullptr);

    int nblk = (NPAD / PNL) * BATCH;    // 512 blocks
    panel_pass<1><<<nblk, 512, 0, stream>>>(Xp, Yp, x2, y2, yr, row_min, out);
    prep_rms<<<(BATCH * NPAD) / 256, 256, 0, stream>>>(row_min, y2, yr);
    panel_pass<2><<<nblk, 512, 0, stream>>>(Xp, Yp, x2, y2, yr, row_min, out);
}

// Round 18
// 192.561 us; speedup vs baseline: 1.3303x; 1.3303x over previous
//
#include <hip/hip_runtime.h>
#include <hip/hip_bf16.h>
#include <stdint.h>

#define IMG_H 96
#define IMG_W 96
#define IMG_C 3
#define HO    90                 // 96-7+1
#define NPAT  8100               // 90*90
#define NPAD  8192
#define DDIM  147                // 3*7*7
#define KPAD  160                // padded K (5 chunks of 32)
#define NCHK  5
#define BATCH 4
#define PNL   64                 // panel rows per block
#define SRT   128                // stream rows per tile
#define NT    (NPAD / SRT)       // 64 stream tiles
#define ALPHA 0.05f
#define QE    3072               // queue slot elems: 5*512 frag + 512 scalar

typedef __attribute__((ext_vector_type(8))) short short8;
typedef __attribute__((ext_vector_type(4))) float f32x4;

__device__ __forceinline__ void async16(const void* g, void* l) {
    __builtin_amdgcn_global_load_lds(
        (const __attribute__((address_space(1))) unsigned int*)g,
        (__attribute__((address_space(3))) unsigned int*)l,
        16, 0, 0);
}

// ---------- fused patch extraction (x and y via grid.z) + norms ----------
__global__ __launch_bounds__(256) void extract_patches(
    const float* __restrict__ imx,          // [B][3][96][96]
    const float* __restrict__ imy,
    __hip_bfloat16* __restrict__ Xp,        // [B][NPAD][KPAD]
    __hip_bfloat16* __restrict__ Yp,
    float* __restrict__ x2,                 // [B][NPAD]
    float* __restrict__ y2,
    float* __restrict__ outzero)
{
    int z    = blockIdx.z;                  // 0 -> x, 1 -> y
    int wid  = threadIdx.x >> 6;
    int lane = threadIdx.x & 63;
    int pidx = blockIdx.x * 4 + wid;        // 0..8191
    int b    = blockIdx.y;
    if (pidx >= NPAD) return;
    if (z == 0 && blockIdx.x == 0 && blockIdx.y == 0 && threadIdx.x == 0)
        outzero[0] = 0.f;
    const float* im = (z ? imy : imx) + (size_t)b * (IMG_C * IMG_H * IMG_W);
    __hip_bfloat16* pp = (z ? Yp : Xp) + ((size_t)b * NPAD + pidx) * KPAD;
    float* nrm = (z ? y2 : x2);
    int r = pidx / HO, c = pidx - r * HO;
    bool valid = pidx < NPAT;
    float ss = 0.f;
    for (int d = lane; d < KPAD; d += 64) {
        float v = 0.f;
        if (valid && d < DDIM) {
            int ch  = d / 49;
            int rem = d - ch * 49;
            int pr  = rem / 7, pc = rem - pr * 7;
            v = im[ch * (IMG_H * IMG_W) + (r + pr) * IMG_W + (c + pc)];
        }
        pp[d] = __float2bfloat16(v);
        ss += v * v;
    }
    for (int s = 32; s; s >>= 1) ss += __shfl_down(ss, s);
    if (lane == 0) nrm[(size_t)b * NPAD + pidx] = ss;
}

// ------------- panel-persistent, per-wave async 3-deep LDS queue -------------
// R16 structure verified (90.9 us/pass): loop unrolled by 3 (queue slot is a
// LITERAL -> imm addressing), monotone staging pointers, exact vmcnt literals
// (6 VMEM per staged tile; steady 12, tail 12/6/0).
// Changes vs R16 (epilogue/overhead only, loop bit-identical):
//  - PASS1 epilogue computes rms and stores (y2, rms) float2 directly (its
//    block owns rows exclusively) -> prep_rms kernel deleted.
//  - pad-select for PASS1's stream x2 only in the final tile body (t=63).
template <int PASS>
__global__ __launch_bounds__(512, 2) void panel_pass(
    const __hip_bfloat16* __restrict__ Xp,   // [B][NPAD][KPAD]
    const __hip_bfloat16* __restrict__ Yp,   // [B][NPAD][KPAD]
    const float* __restrict__ x2,
    const float* __restrict__ y2,
    float2* __restrict__ yr,                 // (y2, rms): PASS1 writes, PASS2 reads
    float* __restrict__ out)                 // PASS2 only
{
    __shared__ __align__(16) __hip_bfloat16 Q[8][3][QE];   // 147456 B

    int blk = blockIdx.x;
    int bz  = blk & 3;               // image: fixed per XCD under %8 rr
    int tP  = blk >> 2;              // panel index 0..127
    int tid = threadIdx.x;
    int wid = tid >> 6, lane = tid & 63;
    int fr  = lane & 15;
    int koq = lane >> 4;             // k-quad 0..3

    const __hip_bfloat16* Pbase =
        (PASS == 1 ? Yp : Xp) + ((size_t)bz * NPAD + tP * PNL) * KPAD;
    const __hip_bfloat16* Sbase =
        (PASS == 1 ? Xp : Yp) + (size_t)bz * NPAD * KPAD;
    const float*  sx2 = x2 + (size_t)bz * NPAD;
    const float2* syr = yr + (size_t)bz * NPAD;

    int srW  = wid * 16;             // wave's stream slice base row
    int slog = (lane & 3) ^ (((lane >> 2) >> 1) & 3);   // store swizzle

    // ---- panel stage (waves 0-3) into Q[0..3][0]; p_reg load; then free ----
    if (wid < 4) {
        const __hip_bfloat16* src = Pbase +
            ((size_t)(wid * 16 + (lane >> 2))) * KPAD + slog * 8;
        __hip_bfloat16* dst = &Q[wid][0][0];
        for (int c = 0; c < NCHK; ++c)
            async16(src + c * 32, dst + c * 512);
    }
    __syncthreads();                 // panel landed (vmcnt drained)

    int sread = (koq ^ ((fr >> 1) & 3)) * 8;            // read swizzle
    short8 p_reg[NCHK][4];
#pragma unroll
    for (int c = 0; c < NCHK; ++c)
#pragma unroll
        for (int m = 0; m < 4; ++m)
            p_reg[c][m] = *(const short8*)&Q[m][0][c * 512 + fr * 32 + sread];

    float xv[4];   // PASS2: panel cols' x2 (direct global, once)
    if (PASS == 2)
#pragma unroll
        for (int nb = 0; nb < 4; ++nb)
            xv[nb] = x2[(size_t)bz * NPAD + tP * PNL + nb * 16 + fr];

    __syncthreads();                 // everyone past panel reads; Q reusable

    float runmin[PASS == 1 ? 16 : 4];
#pragma unroll
    for (int i = 0; i < (PASS == 1 ? 16 : 4); ++i)
        runmin[i] = __builtin_inff();

    // ---- fixed per-lane read bases (all queue reads = base + IMM) ----
    const __hip_bfloat16* qrd = &Q[wid][0][fr * 32 + sread]; // + s*3072 + c*512
    const float*  qs1 = (const float*)&Q[wid][0][2560];      // + s*1536 + fr
    const float2* qs2 = (const float2*)&Q[wid][0][2560];     // + s*768 + idx

    // ---- monotone staging pointers (+= const per staged tile) ----
    const __hip_bfloat16* sfrag =
        Sbase + (size_t)(srW + (lane >> 2)) * KPAD + slog * 8;
    const float*  ss1 = sx2 + srW + (lane < 4 ? lane : 3) * 4;
    const float2* ss2 = syr + srW + (lane < 8 ? lane : 7) * 2;

    auto stage = [&](int slot) {     // slot is a literal at every call site
        __hip_bfloat16* dst = &Q[wid][slot][0];
#pragma unroll
        for (int c = 0; c < NCHK; ++c)
            async16(sfrag + c * 32, dst + c * 512);
        if (PASS == 1) { async16(ss1, dst + 2560); ss1 += SRT; }
        else           { async16(ss2, dst + 2560); ss2 += SRT; }
        sfrag += (size_t)SRT * KPAD;
    };

    auto body = [&](int t, int slot, bool last) {  // slot literal -> imm addr
        short8 f[NCHK];
#pragma unroll
        for (int c = 0; c < NCHK; ++c)
            f[c] = *(const short8*)(qrd + slot * QE + c * 512);

        float xg = 0.f;
        float2 pq[4];
        if (PASS == 1) {
            xg = qs1[slot * 1536 + fr];
            if (last && t * SRT + srW + fr >= NPAT) xg = __builtin_inff();
        } else {
#pragma unroll
            for (int reg = 0; reg < 4; ++reg)
                pq[reg] = qs2[slot * 768 + koq * 4 + reg];
        }

        f32x4 acc[4] = {};
#pragma unroll
        for (int c = 0; c < NCHK; ++c) {
            if (PASS == 1) {
#pragma unroll
                for (int m = 0; m < 4; ++m)
                    acc[m] = __builtin_amdgcn_mfma_f32_16x16x32_bf16(
                        p_reg[c][m], f[c], acc[m], 0, 0, 0);
            } else {
#pragma unroll
                for (int nb = 0; nb < 4; ++nb)
                    acc[nb] = __builtin_amdgcn_mfma_f32_16x16x32_bf16(
                        f[c], p_reg[c][nb], acc[nb], 0, 0, 0);
            }
        }

        if (PASS == 1) {
#pragma unroll
            for (int m = 0; m < 4; ++m)
#pragma unroll
                for (int reg = 0; reg < 4; ++reg)
                    runmin[m * 4 + reg] = fminf(runmin[m * 4 + reg],
                        fmaf(-2.0f, acc[m][reg], xg));
        } else {
#pragma unroll
            for (int reg = 0; reg < 4; ++reg) {
                float yv = pq[reg].x, rr = pq[reg].y;   // rr=inf on pad rows
#pragma unroll
                for (int nb = 0; nb < 4; ++nb)
                    runmin[nb] = fminf(runmin[nb],
                        fmaf(-2.0f, acc[nb][reg], yv + xv[nb]) * rr);
            }
        }
        // this slot's LDS reads returned -> safe to overwrite afterwards
        asm volatile("s_waitcnt lgkmcnt(0)" ::: "memory");
    };

#define W12 asm volatile("s_waitcnt vmcnt(12)" ::: "memory")
    // prologue: 3 tiles in flight (18 VMEM/wave)
    stage(0); stage(1); stage(2);    // tiles 0,1,2

    int t = 0;
#pragma unroll 1
    for (int tt = 0; tt < 19; ++tt) {   // bodies t=0..56, stages tiles 3..59
        W12; body(t, 0, false); stage(0);
        W12; body(t + 1, 1, false); stage(1);
        W12; body(t + 2, 2, false); stage(2);
        t += 3;
    }
    // tail: bodies 57..63, stages tiles 60..63 (slot == tile%3 throughout)
    W12; body(57, 0, false); stage(0);      // tile 60
    W12; body(58, 1, false); stage(1);      // tile 61
    W12; body(59, 2, false); stage(2);      // tile 62
    W12; body(60, 0, false); stage(0);      // tile 63
    W12; body(61, 1, false);
    asm volatile("s_waitcnt vmcnt(6)" ::: "memory"); body(62, 2, false);
    asm volatile("s_waitcnt vmcnt(0)" ::: "memory"); body(63, 0, true);
#undef W12

    // ---- epilogue: red[] aliases queue (dead) ----
    __syncthreads();
    float* red = (float*)&Q[0][0][0];            // [8][PNL]

    if (PASS == 1) {
#pragma unroll
        for (int m = 0; m < 4; ++m)
#pragma unroll
            for (int reg = 0; reg < 4; ++reg) {
                float v = runmin[m * 4 + reg];
                for (int s = 1; s < 16; s <<= 1)
                    v = fminf(v, __shfl_xor(v, s));
                if (fr == 0)
                    red[wid * PNL + m * 16 + koq * 4 + reg] = v;
            }
        __syncthreads();
        if (tid < PNL) {
            int j = tP * PNL + tid;
            float mv = red[tid];
#pragma unroll
            for (int w = 1; w < 8; ++w) mv = fminf(mv, red[w * PNL + tid]);
            float y2g = y2[(size_t)bz * NPAD + j];
            float rm  = fmaxf(y2g + mv, 0.f) * (1.0f / (float)DDIM); // row_min
            float rr  = (j < NPAT) ? (1.0f / (float)DDIM) / (rm + ALPHA)
                                   : __builtin_inff();
            yr[(size_t)bz * NPAD + j] = make_float2(y2g, rr);
        }
    } else {
#pragma unroll
        for (int nb = 0; nb < 4; ++nb) {
            float v = runmin[nb];
            v = fminf(v, __shfl_xor(v, 16));
            v = fminf(v, __shfl_xor(v, 32));
            if (lane < 16) red[wid * PNL + nb * 16 + lane] = v;
        }
        __syncthreads();
        if (tid < PNL) {
            int gc = tP * PNL + tid;
            float cv = red[tid];
#pragma unroll
            for (int w = 1; w < 8; ++w) cv = fminf(cv, red[w * PNL + tid]);
            cv = fmaxf(cv, 0.f);                   // deferred clamp (monotone)
            float s = (gc < NPAT) ? cv : 0.f;      // mask pad cols
            for (int o = 32; o; o >>= 1) s += __shfl_down(s, o);
            if (tid == 0)
                atomicAdd(out, s * (1.0f / (float)(BATCH * NPAT)));
        }
    }
}

extern "C" void kernel_launch(void* const* d_in, const int* in_sizes, int n_in,
                              void* d_out, int out_size, void* d_ws, size_t ws_size,
                              hipStream_t stream) {
    const float* x = (const float*)d_in[0];
    const float* y = (const float*)d_in[1];
    float* out = (float*)d_out;

    char* ws = (char*)d_ws;
    size_t patSz = (size_t)BATCH * NPAD * KPAD * sizeof(__hip_bfloat16); // 10.5 MB
    __hip_bfloat16* Xp = (__hip_bfloat16*)ws;
    __hip_bfloat16* Yp = (__hip_bfloat16*)(ws + patSz);
    float* x2 = (float*)(ws + 2 * patSz);
    float* y2 = x2 + BATCH * NPAD;
    float2* yr = (float2*)(y2 + BATCH * NPAD);

    dim3 eg(NPAD / 4, BATCH, 2);     // z: 0 -> x, 1 -> y
    extract_patches<<<eg, 256, 0, stream>>>(x, y, Xp, Yp, x2, y2, out);

    int nblk = (NPAD / PNL) * BATCH;    // 512 blocks
    panel_pass<1><<<nblk, 512, 0, stream>>>(Xp, Yp, x2, y2, yr, out);
    panel_pass<2><<<nblk, 512, 0, stream>>>(Xp, Yp, x2, y2, yr, out);
}